// Round 1
// baseline (587.060 us; speedup 1.0000x reference)
//
#include <hip/hip_runtime.h>

// Problem constants (fixed by the reference):
//   B=8, N=4096, DIM=C=512, E=8, K=2, H=16, T=B*N=32768
#define T_TOK 32768
#define C_DIM 512
#define N_SEQ 4096

// ---------------------------------------------------------------------------
// K1: gate GEMM  h[t,c] = sum_k x[t,k]*wg1[c,k] + bg1[c]
// fp32, 128x128 tile, BK=16, 256 threads, 8x8 micro-tile per thread.
// Both A (x) and B (wg1) are K-contiguous row-major ("NT" GEMM).
// ---------------------------------------------------------------------------
__global__ __launch_bounds__(256) void k1_gate_gemm(
    const float* __restrict__ X, const float* __restrict__ W,
    const float* __restrict__ bias, float* __restrict__ H) {
  __shared__ float As[16][132];   // [k][m], pad 132 (16B-aligned rows)
  __shared__ float Bs[16][132];   // [k][n]
  const int tid = threadIdx.x;
  const int m0 = blockIdx.y * 128;
  const int n0 = blockIdx.x * 128;
  const int tx = tid & 15, ty = tid >> 4;
  const int sr = tid >> 1;          // staging row 0..127
  const int sk = (tid & 1) * 8;     // staging k offset 0 or 8

  float acc[8][8];
#pragma unroll
  for (int i = 0; i < 8; ++i)
#pragma unroll
    for (int j = 0; j < 8; ++j) acc[i][j] = 0.f;

  const float* xp = X + (m0 + sr) * C_DIM + sk;
  const float* wp = W + (n0 + sr) * C_DIM + sk;

  for (int k0 = 0; k0 < C_DIM; k0 += 16) {
    float4 a0 = *(const float4*)(xp + k0);
    float4 a1 = *(const float4*)(xp + k0 + 4);
    float4 b0 = *(const float4*)(wp + k0);
    float4 b1 = *(const float4*)(wp + k0 + 4);
    __syncthreads();
    As[sk + 0][sr] = a0.x; As[sk + 1][sr] = a0.y;
    As[sk + 2][sr] = a0.z; As[sk + 3][sr] = a0.w;
    As[sk + 4][sr] = a1.x; As[sk + 5][sr] = a1.y;
    As[sk + 6][sr] = a1.z; As[sk + 7][sr] = a1.w;
    Bs[sk + 0][sr] = b0.x; Bs[sk + 1][sr] = b0.y;
    Bs[sk + 2][sr] = b0.z; Bs[sk + 3][sr] = b0.w;
    Bs[sk + 4][sr] = b1.x; Bs[sk + 5][sr] = b1.y;
    Bs[sk + 6][sr] = b1.z; Bs[sk + 7][sr] = b1.w;
    __syncthreads();
#pragma unroll
    for (int kk = 0; kk < 16; ++kk) {
      float a[8], b[8];
      *(float4*)&a[0] = *(const float4*)&As[kk][ty * 8];
      *(float4*)&a[4] = *(const float4*)&As[kk][ty * 8 + 4];
      *(float4*)&b[0] = *(const float4*)&Bs[kk][tx * 8];
      *(float4*)&b[4] = *(const float4*)&Bs[kk][tx * 8 + 4];
#pragma unroll
      for (int i = 0; i < 8; ++i)
#pragma unroll
        for (int j = 0; j < 8; ++j)
          acc[i][j] = fmaf(a[i], b[j], acc[i][j]);
    }
  }

  float bb[8];
  *(float4*)&bb[0] = *(const float4*)(bias + n0 + tx * 8);
  *(float4*)&bb[4] = *(const float4*)(bias + n0 + tx * 8 + 4);
#pragma unroll
  for (int i = 0; i < 8; ++i) {
    float o[8];
#pragma unroll
    for (int j = 0; j < 8; ++j) o[j] = acc[i][j] + bb[j];
    const int row = m0 + ty * 8 + i;
    *(float4*)(H + row * C_DIM + n0 + tx * 8) = *(float4*)&o[0];
    *(float4*)(H + row * C_DIM + n0 + tx * 8 + 4) = *(float4*)&o[4];
  }
}

// ---------------------------------------------------------------------------
// K2: BN batch statistics. Per-thread partials in double, then f64 atomics.
// Grid 128 x 256 threads; each block covers 256 rows; thread covers 2 channels.
// ---------------------------------------------------------------------------
__global__ __launch_bounds__(256) void k2_bn_stats(
    const float* __restrict__ H, double* __restrict__ stats) {
  const int r0 = blockIdx.x * 256;
  const int c1 = threadIdx.x, c2 = threadIdx.x + 256;
  double s1 = 0, q1 = 0, s2 = 0, q2 = 0;
  for (int r = 0; r < 256; ++r) {
    const float* row = H + (r0 + r) * C_DIM;
    float v1 = row[c1], v2 = row[c2];
    s1 += v1; q1 += (double)v1 * v1;
    s2 += v2; q2 += (double)v2 * v2;
  }
  atomicAdd(&stats[c1], s1);
  atomicAdd(&stats[512 + c1], q1);
  atomicAdd(&stats[c2], s2);
  atomicAdd(&stats[512 + c2], q2);
}

// ---------------------------------------------------------------------------
// K3: finalize BN -> scale/shift so that h_bn = h*scale + shift
// ---------------------------------------------------------------------------
__global__ void k3_bn_finalize(const double* __restrict__ stats,
                               const float* __restrict__ gamma,
                               const float* __restrict__ beta,
                               float* __restrict__ scsh) {
  const int c = threadIdx.x;
  const double mu = stats[c] * (1.0 / (double)T_TOK);
  const double var = stats[512 + c] * (1.0 / (double)T_TOK) - mu * mu;
  const double rstd = 1.0 / sqrt(var + 1e-5);
  const float scv = (float)((double)gamma[c] * rstd);
  scsh[c] = scv;
  scsh[512 + c] = beta[c] - (float)mu * scv;
}

// ---------------------------------------------------------------------------
// K4: gating. One wave per token (16 tokens per wave via loop). Computes
// normalized+relu'd h row, 8 logits (lane partials + xor wave reduce),
// top-2 (ties -> lowest index, matching lax.top_k), softmax weights,
// writes selection and accumulates usage.
// Grid 512 x 256 threads (4 waves); block covers 64 tokens.
// ---------------------------------------------------------------------------
__global__ __launch_bounds__(256) void k4_gate(
    const float* __restrict__ H, const float* __restrict__ scsh,
    const float* __restrict__ wg2, const float* __restrict__ bg2,
    int* __restrict__ selE, float* __restrict__ selW,
    float* __restrict__ usage) {
  __shared__ float lus[8];
  if (threadIdx.x < 8) lus[threadIdx.x] = 0.f;
  __syncthreads();

  const int wv = threadIdx.x >> 6, lane = threadIdx.x & 63;
  const int cb = lane * 8;

  float sc[8], sh[8];
#pragma unroll
  for (int i = 0; i < 8; ++i) {
    sc[i] = scsh[cb + i];
    sh[i] = scsh[512 + cb + i];
  }
  float wg[8][8];
#pragma unroll
  for (int e = 0; e < 8; ++e)
#pragma unroll
    for (int i = 0; i < 8; ++i) wg[e][i] = wg2[e * C_DIM + cb + i];
  float bg[8];
#pragma unroll
  for (int e = 0; e < 8; ++e) bg[e] = bg2[e];

  for (int it = 0; it < 16; ++it) {
    const int t = blockIdx.x * 64 + wv * 16 + it;
    const float* hr = H + t * C_DIM + cb;
    float4 h0 = *(const float4*)hr;
    float4 h1 = *(const float4*)(hr + 4);
    float y[8] = {h0.x, h0.y, h0.z, h0.w, h1.x, h1.y, h1.z, h1.w};
#pragma unroll
    for (int i = 0; i < 8; ++i) y[i] = fmaxf(fmaf(y[i], sc[i], sh[i]), 0.f);

    float lg[8];
#pragma unroll
    for (int e = 0; e < 8; ++e) {
      float s = 0.f;
#pragma unroll
      for (int i = 0; i < 8; ++i) s = fmaf(y[i], wg[e][i], s);
      lg[e] = s;
    }
#pragma unroll
    for (int d = 1; d < 64; d <<= 1)
#pragma unroll
      for (int e = 0; e < 8; ++e) lg[e] += __shfl_xor(lg[e], d, 64);
#pragma unroll
    for (int e = 0; e < 8; ++e) lg[e] += bg[e];

    float v1 = lg[0]; int i1 = 0;
#pragma unroll
    for (int e = 1; e < 8; ++e)
      if (lg[e] > v1) { v1 = lg[e]; i1 = e; }
    float v2 = -3.4e38f; int i2 = 0;
#pragma unroll
    for (int e = 0; e < 8; ++e)
      if (e != i1 && lg[e] > v2) { v2 = lg[e]; i2 = e; }

    const float p = expf(v2 - v1);
    const float rw = 1.f / (1.f + p);
    const float w0 = rw, w1 = p * rw;

    if (lane == 0) {
      selE[2 * t] = i1;
      selE[2 * t + 1] = i2;
      selW[2 * t] = w0;
      selW[2 * t + 1] = w1;
      atomicAdd(&lus[i1], w0);
      atomicAdd(&lus[i2], w1);
    }
  }
  __syncthreads();
  if (threadIdx.x < 8) atomicAdd(&usage[threadIdx.x], lus[threadIdx.x]);
}

// ---------------------------------------------------------------------------
// K5: sparse expert compute + transposed output write.
// Block = 256 threads, 64 tokens (same batch b, contiguous n).
// Phase B: t1[2][16] = relu(x @ w1[e] + b1[e]) per token (x staged in LDS).
// Phase C: y[c] = sum_{s,h} (w_s * t1) * w2[e_s][h][c] + sum_s w_s*b2[e_s][c],
//          staged through LDS as [c][n] tiles for coalesced [B,C,N] stores.
// ---------------------------------------------------------------------------
__global__ __launch_bounds__(256) void k5_expert(
    const float* __restrict__ X, const float* __restrict__ W1,
    const float* __restrict__ B1, const float* __restrict__ W2,
    const float* __restrict__ B2, const int* __restrict__ selE,
    const float* __restrict__ selW, float* __restrict__ Out) {
  __shared__ float xs[64][68];   // token-major x chunk, padded
  __shared__ float uu[64][33];   // weighted relu'd t1 per token (2x16)
  __shared__ float ys[64][67];   // [c_local][token] output staging
  __shared__ int sE[64][2];
  __shared__ float sWt[64][2];

  const int tid = threadIdx.x;
  const int t0 = blockIdx.x * 64;
  const int bi = t0 >> 12;       // t0 / 4096
  const int n0 = t0 & 4095;

  if (tid < 128) {
    sE[tid >> 1][tid & 1] = selE[t0 * 2 + tid];
    sWt[tid >> 1][tid & 1] = selW[t0 * 2 + tid];
  }
  __syncthreads();

  const int tt = tid >> 2, q = tid & 3, q4 = q * 4, q16 = q * 16;
  const int e0 = sE[tt][0], e1 = sE[tt][1];
  const float w0 = sWt[tt][0], w1w = sWt[tt][1];

  // ---- Phase B: FC1 for the two selected experts --------------------------
  float4 A0 = make_float4(0.f, 0.f, 0.f, 0.f);
  float4 A1 = make_float4(0.f, 0.f, 0.f, 0.f);
  for (int c0 = 0; c0 < C_DIM; c0 += 64) {
    __syncthreads();
    {
      const float* src = X + (t0 + tt) * C_DIM + c0 + q16;
      float4 v0 = *(const float4*)(src);
      float4 v1 = *(const float4*)(src + 4);
      float4 v2 = *(const float4*)(src + 8);
      float4 v3 = *(const float4*)(src + 12);
      *(float4*)&xs[tt][q16] = v0;
      *(float4*)&xs[tt][q16 + 4] = v1;
      *(float4*)&xs[tt][q16 + 8] = v2;
      *(float4*)&xs[tt][q16 + 12] = v3;
    }
    __syncthreads();
    const float* w1p0 = W1 + (e0 * 512 + c0) * 16 + q4;
    const float* w1p1 = W1 + (e1 * 512 + c0) * 16 + q4;
#pragma unroll 8
    for (int cc = 0; cc < 64; ++cc) {
      const float xv = xs[tt][cc];
      float4 wa = *(const float4*)(w1p0 + cc * 16);
      float4 wb = *(const float4*)(w1p1 + cc * 16);
      A0.x = fmaf(xv, wa.x, A0.x); A0.y = fmaf(xv, wa.y, A0.y);
      A0.z = fmaf(xv, wa.z, A0.z); A0.w = fmaf(xv, wa.w, A0.w);
      A1.x = fmaf(xv, wb.x, A1.x); A1.y = fmaf(xv, wb.y, A1.y);
      A1.z = fmaf(xv, wb.z, A1.z); A1.w = fmaf(xv, wb.w, A1.w);
    }
  }
  {
    float4 bb0 = *(const float4*)(B1 + e0 * 16 + q4);
    float4 bb1 = *(const float4*)(B1 + e1 * 16 + q4);
    uu[tt][q4 + 0] = fmaxf(A0.x + bb0.x, 0.f) * w0;
    uu[tt][q4 + 1] = fmaxf(A0.y + bb0.y, 0.f) * w0;
    uu[tt][q4 + 2] = fmaxf(A0.z + bb0.z, 0.f) * w0;
    uu[tt][q4 + 3] = fmaxf(A0.w + bb0.w, 0.f) * w0;
    uu[tt][16 + q4 + 0] = fmaxf(A1.x + bb1.x, 0.f) * w1w;
    uu[tt][16 + q4 + 1] = fmaxf(A1.y + bb1.y, 0.f) * w1w;
    uu[tt][16 + q4 + 2] = fmaxf(A1.z + bb1.z, 0.f) * w1w;
    uu[tt][16 + q4 + 3] = fmaxf(A1.w + bb1.w, 0.f) * w1w;
  }
  __syncthreads();

  // ---- Phase C: FC2 combine + transpose write -----------------------------
  for (int c0 = 0; c0 < C_DIM; c0 += 64) {
    float4 acc0, acc1, acc2, acc3;
    {
      const float* b2p0 = B2 + e0 * 512 + c0 + q16;
      const float* b2p1 = B2 + e1 * 512 + c0 + q16;
      float4 x0 = *(const float4*)(b2p0);
      float4 x1 = *(const float4*)(b2p0 + 4);
      float4 x2 = *(const float4*)(b2p0 + 8);
      float4 x3 = *(const float4*)(b2p0 + 12);
      float4 z0 = *(const float4*)(b2p1);
      float4 z1 = *(const float4*)(b2p1 + 4);
      float4 z2 = *(const float4*)(b2p1 + 8);
      float4 z3 = *(const float4*)(b2p1 + 12);
      acc0.x = fmaf(w0, x0.x, w1w * z0.x); acc0.y = fmaf(w0, x0.y, w1w * z0.y);
      acc0.z = fmaf(w0, x0.z, w1w * z0.z); acc0.w = fmaf(w0, x0.w, w1w * z0.w);
      acc1.x = fmaf(w0, x1.x, w1w * z1.x); acc1.y = fmaf(w0, x1.y, w1w * z1.y);
      acc1.z = fmaf(w0, x1.z, w1w * z1.z); acc1.w = fmaf(w0, x1.w, w1w * z1.w);
      acc2.x = fmaf(w0, x2.x, w1w * z2.x); acc2.y = fmaf(w0, x2.y, w1w * z2.y);
      acc2.z = fmaf(w0, x2.z, w1w * z2.z); acc2.w = fmaf(w0, x2.w, w1w * z2.w);
      acc3.x = fmaf(w0, x3.x, w1w * z3.x); acc3.y = fmaf(w0, x3.y, w1w * z3.y);
      acc3.z = fmaf(w0, x3.z, w1w * z3.z); acc3.w = fmaf(w0, x3.w, w1w * z3.w);
    }
#pragma unroll
    for (int s = 0; s < 2; ++s) {
      const int e = s ? e1 : e0;
      const float* wp = W2 + e * 8192 + c0 + q16;
#pragma unroll 4
      for (int hh = 0; hh < 16; ++hh) {
        const float uv = uu[tt][s * 16 + hh];
        const float* w4p = wp + hh * 512;
        float4 y0 = *(const float4*)(w4p);
        float4 y1 = *(const float4*)(w4p + 4);
        float4 y2 = *(const float4*)(w4p + 8);
        float4 y3 = *(const float4*)(w4p + 12);
        acc0.x = fmaf(uv, y0.x, acc0.x); acc0.y = fmaf(uv, y0.y, acc0.y);
        acc0.z = fmaf(uv, y0.z, acc0.z); acc0.w = fmaf(uv, y0.w, acc0.w);
        acc1.x = fmaf(uv, y1.x, acc1.x); acc1.y = fmaf(uv, y1.y, acc1.y);
        acc1.z = fmaf(uv, y1.z, acc1.z); acc1.w = fmaf(uv, y1.w, acc1.w);
        acc2.x = fmaf(uv, y2.x, acc2.x); acc2.y = fmaf(uv, y2.y, acc2.y);
        acc2.z = fmaf(uv, y2.z, acc2.z); acc2.w = fmaf(uv, y2.w, acc2.w);
        acc3.x = fmaf(uv, y3.x, acc3.x); acc3.y = fmaf(uv, y3.y, acc3.y);
        acc3.z = fmaf(uv, y3.z, acc3.z); acc3.w = fmaf(uv, y3.w, acc3.w);
      }
    }
    // stage transposed
    ys[q16 + 0][tt] = acc0.x;  ys[q16 + 1][tt] = acc0.y;
    ys[q16 + 2][tt] = acc0.z;  ys[q16 + 3][tt] = acc0.w;
    ys[q16 + 4][tt] = acc1.x;  ys[q16 + 5][tt] = acc1.y;
    ys[q16 + 6][tt] = acc1.z;  ys[q16 + 7][tt] = acc1.w;
    ys[q16 + 8][tt] = acc2.x;  ys[q16 + 9][tt] = acc2.y;
    ys[q16 + 10][tt] = acc2.z; ys[q16 + 11][tt] = acc2.w;
    ys[q16 + 12][tt] = acc3.x; ys[q16 + 13][tt] = acc3.y;
    ys[q16 + 14][tt] = acc3.z; ys[q16 + 15][tt] = acc3.w;
    __syncthreads();
#pragma unroll
    for (int i = 0; i < 16; ++i) {
      const int cl = i * 4 + (tid >> 6);
      const int nn = tid & 63;
      Out[(bi * C_DIM + c0 + cl) * N_SEQ + n0 + nn] = ys[cl][nn];
    }
    __syncthreads();
  }
}

// ---------------------------------------------------------------------------
// K6: load-balance loss
// ---------------------------------------------------------------------------
__global__ void k6_lb(const float* __restrict__ usage, float* __restrict__ outlb) {
  float s = 0.f;
#pragma unroll
  for (int e = 0; e < 8; ++e) {
    const float u = usage[e] * (1.f / (float)T_TOK);
    s += u * u;
  }
  outlb[0] = s * 8.f;
}

// ---------------------------------------------------------------------------
extern "C" void kernel_launch(void* const* d_in, const int* in_sizes, int n_in,
                              void* d_out, int out_size, void* d_ws, size_t ws_size,
                              hipStream_t stream) {
  const float* x    = (const float*)d_in[0];
  const float* wg1  = (const float*)d_in[1];
  const float* bg1  = (const float*)d_in[2];
  const float* gamma= (const float*)d_in[3];
  const float* beta = (const float*)d_in[4];
  const float* wg2  = (const float*)d_in[5];
  const float* bg2  = (const float*)d_in[6];
  const float* w1   = (const float*)d_in[7];
  const float* b1   = (const float*)d_in[8];
  const float* w2   = (const float*)d_in[9];
  const float* b2   = (const float*)d_in[10];
  float* out = (float*)d_out;

  // Workspace layout (bytes):
  //   [0, 67108864)            h [T, C] fp32
  //   [67108864, 67117056)     stats double[1024] (sum[512], sumsq[512])
  //   [67117056, 67121152)     scsh float[1024] (scale[512], shift[512])
  //   [67121152, 67121184)     usage float[8]
  //   [67121184, 67383328)     selE int[2T]
  //   [67383328, 67645472)     selW float[2T]
  char* ws = (char*)d_ws;
  float* h = (float*)ws;
  double* statsD = (double*)(ws + 67108864);
  float* scsh = (float*)(ws + 67117056);
  float* usage = (float*)(ws + 67121152);
  int* selE = (int*)(ws + 67121184);
  float* selW = (float*)(ws + 67383328);

  // zero stats + scsh + usage (12320 bytes)
  hipMemsetAsync(ws + 67108864, 0, 12320, stream);

  k1_gate_gemm<<<dim3(4, 256), 256, 0, stream>>>(x, wg1, bg1, h);
  k2_bn_stats<<<128, 256, 0, stream>>>(h, statsD);
  k3_bn_finalize<<<1, 512, 0, stream>>>(statsD, gamma, beta, scsh);
  k4_gate<<<512, 256, 0, stream>>>(h, scsh, wg2, bg2, selE, selW, usage);
  k5_expert<<<512, 256, 0, stream>>>(x, w1, b1, w2, b2, selE, selW, out);
  k6_lb<<<1, 1, 0, stream>>>(usage, out + (size_t)16777216);
}

// Round 3
// 278.200 us; speedup vs baseline: 2.1102x; 2.1102x over previous
//
#include <hip/hip_runtime.h>

// Problem constants: B=8, N=4096, DIM=C=512, E=8, K=2, H=16, T=B*N=32768
#define T_TOK 32768
#define C_DIM 512
#define N_SEQ 4096

typedef unsigned short ushort_t;
typedef unsigned int uint_t;
typedef __attribute__((ext_vector_type(8))) _Float16 half8;
typedef __attribute__((ext_vector_type(4))) float f32x4;

static __device__ __forceinline__ ushort_t f2h_bits(float f) {
  _Float16 h = (_Float16)f;
  return __builtin_bit_cast(ushort_t, h);
}
static __device__ __forceinline__ float h_bits2f(ushort_t u) {
  return (float)__builtin_bit_cast(_Float16, u);
}

// LDS tile: 128 rows x 32 f16 (64B rows), stored in 16B slots with XOR swizzle
// slot p holds logical (r = p>>2, q = (p&3) ^ ((r>>1)&3)). Fragment read for
// (row r, k-quarter q) -> ushort off r*32 + (q ^ ((r>>1)&3))*8. This gives
// 2-way (free) bank aliasing on ds_read_b128 instead of 8-way.
static __device__ __forceinline__ half8 frag_ld(const ushort_t* base, int r, int q) {
  const int off = r * 32 + ((q ^ ((r >> 1) & 3)) * 8);  // in ushorts
  return *(const half8*)(base + off);
}

#define GLOAD_LDS(gptr, lptr)                                                  \
  __builtin_amdgcn_global_load_lds(                                            \
      (const __attribute__((address_space(1))) uint_t*)(gptr),                 \
      (__attribute__((address_space(3))) uint_t*)(lptr), 16, 0, 0)

// ---------------------------------------------------------------------------
// prep_x: x fp32 -> f16 hi/lo split arrays. 8 elements per thread.
// hi = f16(x), lo = f16(x - hi): together capture ~2^-24 of x.
// ---------------------------------------------------------------------------
__global__ __launch_bounds__(256) void prep_x(const float* __restrict__ X,
                                              ushort_t* __restrict__ Ahi,
                                              ushort_t* __restrict__ Alo) {
  const size_t i0 = ((size_t)blockIdx.x * 256 + threadIdx.x) * 8;
  float4 a = *(const float4*)(X + i0);
  float4 b = *(const float4*)(X + i0 + 4);
  float v[8] = {a.x, a.y, a.z, a.w, b.x, b.y, b.z, b.w};
  ushort_t hi[8], lo[8];
#pragma unroll
  for (int j = 0; j < 8; ++j) {
    hi[j] = f2h_bits(v[j]);
    lo[j] = f2h_bits(v[j] - h_bits2f(hi[j]));
  }
  *(uint4*)(Ahi + i0) = *(uint4*)hi;
  *(uint4*)(Alo + i0) = *(uint4*)lo;
}

// ---------------------------------------------------------------------------
// prep_w: wg1 -> f16 hi/lo; w1 -> W1t [128 eh][512 c] f16;
// w2+b2 -> W2t [512 c][160 k] f16 (k<128: w2[e][h][c]; k=128+e: b2[e][c]; else 0)
// ---------------------------------------------------------------------------
__global__ __launch_bounds__(256) void prep_w(
    const float* __restrict__ wg1, const float* __restrict__ w1,
    const float* __restrict__ w2, const float* __restrict__ b2,
    ushort_t* __restrict__ Whi, ushort_t* __restrict__ Wlo,
    ushort_t* __restrict__ W1t, ushort_t* __restrict__ W2t) {
  const int idx = blockIdx.x * 256 + threadIdx.x;  // grid 1024 -> 262144
  {
    const float v = wg1[idx];
    const ushort_t h = f2h_bits(v);
    Whi[idx] = h;
    Wlo[idx] = f2h_bits(v - h_bits2f(h));
  }
  if (idx < 65536) {
    const int eh = idx >> 9, c = idx & 511;
    const int e = eh >> 4, hh = eh & 15;
    W1t[idx] = f2h_bits(w1[((size_t)e * 512 + c) * 16 + hh]);
  }
  if (idx < 81920) {
    const int c = idx / 160, k = idx - c * 160;
    float v = 0.f;
    if (k < 128) {
      const int e = k >> 4, hh = k & 15;
      v = w2[((size_t)e * 16 + hh) * 512 + c];
    } else if (k < 136) {
      v = b2[(size_t)(k - 128) * 512 + c];
    }
    W2t[c * 160 + k] = f2h_bits(v);
  }
}

// ---------------------------------------------------------------------------
// K1: gate GEMM via split-f16 MFMA, h = (xhi+xlo)@(whi+wlo)^T + bg1
// (3 products, lo*lo dropped ~2^-24). 128x128 tile, BK=32, 4 waves,
// global_load_lds staging. Epilogue: h fp32 + BN partial sums (fp32 atomics).
// ---------------------------------------------------------------------------
__global__ __launch_bounds__(256) void k1_mfma(
    const ushort_t* __restrict__ Ahi, const ushort_t* __restrict__ Alo,
    const ushort_t* __restrict__ Whi, const ushort_t* __restrict__ Wlo,
    const float* __restrict__ bg1, float* __restrict__ H,
    float* __restrict__ stats) {
  __shared__ ushort_t sAh[4096], sAl[4096], sBh[4096], sBl[4096];
  const int tid = threadIdx.x, lane = tid & 63, w = tid >> 6;
  const int wm = w >> 1, wn = w & 1;
  const int m0 = blockIdx.y * 128, n0 = blockIdx.x * 128;

  const ushort_t* gsrc;
  ushort_t* lbase;
  int rowbase;
  if (w == 0)      { gsrc = Ahi; lbase = sAh; rowbase = m0; }
  else if (w == 1) { gsrc = Alo; lbase = sAl; rowbase = m0; }
  else if (w == 2) { gsrc = Whi; lbase = sBh; rowbase = n0; }
  else             { gsrc = Wlo; lbase = sBl; rowbase = n0; }

  f32x4 acc[4][4] = {};
  const int cl = lane & 15, qf = lane >> 4;

  for (int kc = 0; kc < 16; ++kc) {
    const int k0 = kc * 32;
    __syncthreads();
#pragma unroll
    for (int j = 0; j < 8; ++j) {
      const int p = j * 64 + lane;
      const int r = p >> 2, q = (p & 3) ^ ((r >> 1) & 3);
      GLOAD_LDS(gsrc + (size_t)(rowbase + r) * 512 + k0 + q * 8, lbase + j * 512);
    }
    __syncthreads();
    half8 ah[4], al[4], bh[4], bl[4];
#pragma unroll
    for (int f = 0; f < 4; ++f) {
      ah[f] = frag_ld(sAh, wm * 64 + f * 16 + cl, qf);
      al[f] = frag_ld(sAl, wm * 64 + f * 16 + cl, qf);
      bh[f] = frag_ld(sBh, wn * 64 + f * 16 + cl, qf);
      bl[f] = frag_ld(sBl, wn * 64 + f * 16 + cl, qf);
    }
#pragma unroll
    for (int i = 0; i < 4; ++i)
#pragma unroll
      for (int j = 0; j < 4; ++j) {
        acc[i][j] = __builtin_amdgcn_mfma_f32_16x16x32_f16(ah[i], bh[j], acc[i][j], 0, 0, 0);
        acc[i][j] = __builtin_amdgcn_mfma_f32_16x16x32_f16(ah[i], bl[j], acc[i][j], 0, 0, 0);
        acc[i][j] = __builtin_amdgcn_mfma_f32_16x16x32_f16(al[i], bh[j], acc[i][j], 0, 0, 0);
      }
  }

  // epilogue: +bg1, store h, BN partial stats
  float s[4] = {0, 0, 0, 0}, qs[4] = {0, 0, 0, 0};
  const int rq = lane >> 4;
#pragma unroll
  for (int nf = 0; nf < 4; ++nf) {
    const int col = n0 + wn * 64 + nf * 16 + cl;
    const float bv = bg1[col];
#pragma unroll
    for (int mf = 0; mf < 4; ++mf) {
      const int row = m0 + wm * 64 + mf * 16 + rq * 4;
#pragma unroll
      for (int i = 0; i < 4; ++i) {
        const float v = acc[mf][nf][i] + bv;
        H[(size_t)(row + i) * 512 + col] = v;
        s[nf] += v;
        qs[nf] += v * v;
      }
    }
  }
#pragma unroll
  for (int nf = 0; nf < 4; ++nf) {
    s[nf] += __shfl_xor(s[nf], 16, 64);
    qs[nf] += __shfl_xor(qs[nf], 16, 64);
    s[nf] += __shfl_xor(s[nf], 32, 64);
    qs[nf] += __shfl_xor(qs[nf], 32, 64);
  }
  if (lane < 16) {
#pragma unroll
    for (int nf = 0; nf < 4; ++nf) {
      const int col = n0 + wn * 64 + nf * 16 + cl;
      atomicAdd(&stats[col], s[nf]);
      atomicAdd(&stats[512 + col], qs[nf]);
    }
  }
}

// ---------------------------------------------------------------------------
// K3: finalize BN -> scale/shift so that h_bn = h*scale + shift
// ---------------------------------------------------------------------------
__global__ void k3_bn_finalize(const float* __restrict__ stats,
                               const float* __restrict__ gamma,
                               const float* __restrict__ beta,
                               float* __restrict__ scsh) {
  const int c = threadIdx.x;
  const double mu = (double)stats[c] * (1.0 / (double)T_TOK);
  const double var = (double)stats[512 + c] * (1.0 / (double)T_TOK) - mu * mu;
  const double rstd = 1.0 / sqrt(var + 1e-5);
  const float scv = (float)((double)gamma[c] * rstd);
  scsh[c] = scv;
  scsh[512 + c] = beta[c] - (float)mu * scv;
}

// ---------------------------------------------------------------------------
// K4: gating (top-2 + softmax + usage). One wave per token group.
// ---------------------------------------------------------------------------
__global__ __launch_bounds__(256) void k4_gate(
    const float* __restrict__ H, const float* __restrict__ scsh,
    const float* __restrict__ wg2, const float* __restrict__ bg2,
    int* __restrict__ selE, float* __restrict__ selW,
    float* __restrict__ usage) {
  __shared__ float lus[8];
  if (threadIdx.x < 8) lus[threadIdx.x] = 0.f;
  __syncthreads();

  const int wv = threadIdx.x >> 6, lane = threadIdx.x & 63;
  const int cb = lane * 8;

  float sc[8], sh[8];
#pragma unroll
  for (int i = 0; i < 8; ++i) {
    sc[i] = scsh[cb + i];
    sh[i] = scsh[512 + cb + i];
  }
  float wg[8][8];
#pragma unroll
  for (int e = 0; e < 8; ++e)
#pragma unroll
    for (int i = 0; i < 8; ++i) wg[e][i] = wg2[e * C_DIM + cb + i];
  float bg[8];
#pragma unroll
  for (int e = 0; e < 8; ++e) bg[e] = bg2[e];

  for (int it = 0; it < 16; ++it) {
    const int t = blockIdx.x * 64 + wv * 16 + it;
    const float* hr = H + (size_t)t * C_DIM + cb;
    float4 h0 = *(const float4*)hr;
    float4 h1 = *(const float4*)(hr + 4);
    float y[8] = {h0.x, h0.y, h0.z, h0.w, h1.x, h1.y, h1.z, h1.w};
#pragma unroll
    for (int i = 0; i < 8; ++i) y[i] = fmaxf(fmaf(y[i], sc[i], sh[i]), 0.f);

    float lg[8];
#pragma unroll
    for (int e = 0; e < 8; ++e) {
      float sum = 0.f;
#pragma unroll
      for (int i = 0; i < 8; ++i) sum = fmaf(y[i], wg[e][i], sum);
      lg[e] = sum;
    }
#pragma unroll
    for (int d = 1; d < 64; d <<= 1)
#pragma unroll
      for (int e = 0; e < 8; ++e) lg[e] += __shfl_xor(lg[e], d, 64);
#pragma unroll
    for (int e = 0; e < 8; ++e) lg[e] += bg[e];

    float v1 = lg[0]; int i1 = 0;
#pragma unroll
    for (int e = 1; e < 8; ++e)
      if (lg[e] > v1) { v1 = lg[e]; i1 = e; }
    float v2 = -3.4e38f; int i2 = 0;
#pragma unroll
    for (int e = 0; e < 8; ++e)
      if (e != i1 && lg[e] > v2) { v2 = lg[e]; i2 = e; }

    const float p = expf(v2 - v1);
    const float rw = 1.f / (1.f + p);
    const float w0 = rw, w1 = p * rw;

    if (lane == 0) {
      selE[2 * t] = i1;
      selE[2 * t + 1] = i2;
      selW[2 * t] = w0;
      selW[2 * t + 1] = w1;
      atomicAdd(&lus[i1], w0);
      atomicAdd(&lus[i2], w1);
    }
  }
  __syncthreads();
  if (threadIdx.x < 8) atomicAdd(&usage[threadIdx.x], lus[threadIdx.x]);
}

// ---------------------------------------------------------------------------
// K5a: FC1 dense-ified MFMA: C[128 tok x 128 eh] = x_hi @ W1t^T, then
// +b1, relu, * gate weight (0 if unselected) -> P f16 [T][160] global.
// Ext cols 128+e hold gate weight (for the b2 K-extension), 136..159 zero.
// ---------------------------------------------------------------------------
__global__ __launch_bounds__(256) void k5a_fc1(
    const ushort_t* __restrict__ Ahi, const ushort_t* __restrict__ W1t,
    const float* __restrict__ b1, const int* __restrict__ selE,
    const float* __restrict__ selW, ushort_t* __restrict__ Pg) {
  __shared__ ushort_t sA[4096], sB[4096];
  __shared__ ushort_t Pl[128 * 160];
  __shared__ float wtab[128 * 8];
  const int tid = threadIdx.x, lane = tid & 63, w = tid >> 6;
  const int wm = w >> 1, wn = w & 1;
  const int t0 = blockIdx.x * 128;

  // prologue: zero wtab + ALL 32 ext cols (2x uint4 = 16 ushorts per thread;
  // 2 threads/row cover [128,160)). Round-2 bug: only half were zeroed ->
  // LDS garbage (possible NaN/Inf f16 patterns) leaked into P.
#pragma unroll
  for (int i = 0; i < 4; ++i) wtab[tid * 4 + i] = 0.f;
  {
    uint4 z = {0, 0, 0, 0};
    const int row = tid >> 1, hf = tid & 1;
    *(uint4*)&Pl[row * 160 + 128 + hf * 16] = z;
    *(uint4*)&Pl[row * 160 + 136 + hf * 16] = z;
  }
  __syncthreads();
  {
    const int t = tid >> 1, s = tid & 1;
    const int e = selE[(size_t)(t0 + t) * 2 + s];
    const float wv = selW[(size_t)(t0 + t) * 2 + s];
    wtab[t * 8 + e] = wv;
    Pl[t * 160 + 128 + e] = f2h_bits(wv);
  }

  f32x4 acc[4][4] = {};
  const int cl = lane & 15, qf = lane >> 4;
  for (int kc = 0; kc < 16; ++kc) {
    const int k0 = kc * 32;
    __syncthreads();
    const ushort_t* gs = (w < 2) ? Ahi : W1t;
    ushort_t* lb = (w < 2) ? sA : sB;
    const int rbase = (w < 2) ? t0 : 0;
    const int wh = w & 1;
#pragma unroll
    for (int j = 0; j < 4; ++j) {
      const int p = wh * 256 + j * 64 + lane;
      const int r = p >> 2, q = (p & 3) ^ ((r >> 1) & 3);
      GLOAD_LDS(gs + (size_t)(rbase + r) * 512 + k0 + q * 8, lb + wh * 2048 + j * 512);
    }
    __syncthreads();
    half8 af[4], bf[4];
#pragma unroll
    for (int f = 0; f < 4; ++f) {
      af[f] = frag_ld(sA, wm * 64 + f * 16 + cl, qf);
      bf[f] = frag_ld(sB, wn * 64 + f * 16 + cl, qf);
    }
#pragma unroll
    for (int i = 0; i < 4; ++i)
#pragma unroll
      for (int j = 0; j < 4; ++j)
        acc[i][j] = __builtin_amdgcn_mfma_f32_16x16x32_f16(af[i], bf[j], acc[i][j], 0, 0, 0);
  }

  // epilogue: bias, relu, gate-weight, pack to Pl (e is wave-uniform per nf)
  {
    const int rq = lane >> 4;
#pragma unroll
    for (int nf = 0; nf < 4; ++nf) {
      const int col = wn * 64 + nf * 16 + cl;
      const float bv = b1[col];
      const int e = wn * 4 + nf;  // col>>4
#pragma unroll
      for (int mf = 0; mf < 4; ++mf) {
        const int row = wm * 64 + mf * 16 + rq * 4;
#pragma unroll
        for (int i = 0; i < 4; ++i) {
          const float v = fmaxf(acc[mf][nf][i] + bv, 0.f) * wtab[(row + i) * 8 + e];
          Pl[(row + i) * 160 + col] = f2h_bits(v);
        }
      }
    }
  }
  __syncthreads();
  // coalesced P store: 128 rows x 320B
  {
    const int row = tid >> 1, half = tid & 1;
    const uint4* src = (const uint4*)&Pl[row * 160 + half * 80];
    uint4* dst = (uint4*)(Pg + (size_t)(t0 + row) * 160 + half * 80);
#pragma unroll
    for (int j = 0; j < 10; ++j) dst[j] = src[j];
  }
}

// ---------------------------------------------------------------------------
// K5b: FC2: Out[128 tok x 512 c] = P_ext @ W2t_ext^T (K=160 incl b2 cols),
// 4 n-chunks of 128, LDS transpose (two token-halves) -> coalesced [B,C,N].
// ---------------------------------------------------------------------------
__global__ __launch_bounds__(256) void k5b_fc2(
    const ushort_t* __restrict__ Pg, const ushort_t* __restrict__ W2t,
    float* __restrict__ Out) {
  __shared__ ushort_t sA[4096], sB[4096];
  __shared__ float ys[128 * 68];
  const int tid = threadIdx.x, lane = tid & 63, w = tid >> 6;
  const int wm = w >> 1, wn = w & 1;
  const int t0 = blockIdx.x * 128;
  const int bi = t0 >> 12, n0 = t0 & 4095;
  const int cl = lane & 15, qf = lane >> 4, rq = lane >> 4;

  for (int nc = 0; nc < 4; ++nc) {
    f32x4 acc[4][4] = {};
    for (int kc = 0; kc < 5; ++kc) {
      const int k0 = kc * 32;
      __syncthreads();
      const ushort_t* gs = (w < 2) ? Pg : W2t;
      ushort_t* lb = (w < 2) ? sA : sB;
      const int rbase = (w < 2) ? t0 : nc * 128;
      const int wh = w & 1;
#pragma unroll
      for (int j = 0; j < 4; ++j) {
        const int p = wh * 256 + j * 64 + lane;
        const int r = p >> 2, q = (p & 3) ^ ((r >> 1) & 3);
        GLOAD_LDS(gs + (size_t)(rbase + r) * 160 + k0 + q * 8, lb + wh * 2048 + j * 512);
      }
      __syncthreads();
      half8 af[4], bf4[4];
#pragma unroll
      for (int f = 0; f < 4; ++f) {
        af[f] = frag_ld(sA, wm * 64 + f * 16 + cl, qf);
        bf4[f] = frag_ld(sB, wn * 64 + f * 16 + cl, qf);
      }
#pragma unroll
      for (int i = 0; i < 4; ++i)
#pragma unroll
        for (int j = 0; j < 4; ++j)
          acc[i][j] = __builtin_amdgcn_mfma_f32_16x16x32_f16(af[i], bf4[j], acc[i][j], 0, 0, 0);
    }
    // transpose + store, two token-half phases
#pragma unroll
    for (int half = 0; half < 2; ++half) {
      __syncthreads();
      if (wm == half) {
#pragma unroll
        for (int nf = 0; nf < 4; ++nf) {
          const int c = wn * 64 + nf * 16 + cl;
#pragma unroll
          for (int mf = 0; mf < 4; ++mf) {
            const int trow = mf * 16 + rq * 4;
#pragma unroll
            for (int i = 0; i < 4; ++i) ys[c * 68 + trow + i] = acc[mf][nf][i];
          }
        }
      }
      __syncthreads();
#pragma unroll
      for (int pass = 0; pass < 8; ++pass) {
        const int c = pass * 16 + (tid >> 4);
        const int f4 = tid & 15;
        float4 v = *(const float4*)&ys[c * 68 + f4 * 4];
        *(float4*)&Out[((size_t)(bi * 512 + nc * 128 + c)) * 4096 + n0 + half * 64 + f4 * 4] = v;
      }
    }
  }
}

// ---------------------------------------------------------------------------
// K6: load-balance loss
// ---------------------------------------------------------------------------
__global__ void k6_lb(const float* __restrict__ usage, float* __restrict__ outlb) {
  float s = 0.f;
#pragma unroll
  for (int e = 0; e < 8; ++e) {
    const float u = usage[e] * (1.f / (float)T_TOK);
    s += u * u;
  }
  outlb[0] = s * 8.f;
}

// ---------------------------------------------------------------------------
extern "C" void kernel_launch(void* const* d_in, const int* in_sizes, int n_in,
                              void* d_out, int out_size, void* d_ws, size_t ws_size,
                              hipStream_t stream) {
  const float* x     = (const float*)d_in[0];
  const float* wg1   = (const float*)d_in[1];
  const float* bg1   = (const float*)d_in[2];
  const float* gamma = (const float*)d_in[3];
  const float* beta  = (const float*)d_in[4];
  const float* wg2   = (const float*)d_in[5];
  const float* bg2   = (const float*)d_in[6];
  const float* w1    = (const float*)d_in[7];
  const float* b1    = (const float*)d_in[8];
  const float* w2    = (const float*)d_in[9];
  const float* b2    = (const float*)d_in[10];
  float* out = (float*)d_out;

  // Workspace layout (bytes):
  char* ws = (char*)d_ws;
  float*    h     = (float*)ws;                          // 67108864
  ushort_t* Ahi   = (ushort_t*)(ws + 67108864);          // 33554432
  ushort_t* Alo   = (ushort_t*)(ws + 100663296);         // 33554432
  ushort_t* Pg    = (ushort_t*)(ws + 134217728);         // 10485760
  ushort_t* Whi   = (ushort_t*)(ws + 144703488);         // 524288
  ushort_t* Wlo   = (ushort_t*)(ws + 145227776);         // 524288
  ushort_t* W1t   = (ushort_t*)(ws + 145752064);         // 131072
  ushort_t* W2t   = (ushort_t*)(ws + 145883136);         // 163840
  float*    stats = (float*)(ws + 146046976);            // 4096
  float*    scsh  = (float*)(ws + 146051072);            // 4096
  float*    usage = (float*)(ws + 146055168);            // 32 (+pad)
  int*      selE  = (int*)(ws + 146055232);              // 262144
  float*    selW  = (float*)(ws + 146317376);            // 262144

  hipMemsetAsync(ws + 146046976, 0, 8224, stream);

  prep_x<<<8192, 256, 0, stream>>>(x, Ahi, Alo);
  prep_w<<<1024, 256, 0, stream>>>(wg1, w1, w2, b2, Whi, Wlo, W1t, W2t);
  k1_mfma<<<dim3(4, 256), 256, 0, stream>>>(Ahi, Alo, Whi, Wlo, bg1, h, stats);
  k3_bn_finalize<<<1, 512, 0, stream>>>(stats, gamma, beta, scsh);
  k4_gate<<<512, 256, 0, stream>>>(h, scsh, wg2, bg2, selE, selW, usage);
  k5a_fc1<<<256, 256, 0, stream>>>(Ahi, W1t, b1, selE, selW, Pg);
  k5b_fc2<<<256, 256, 0, stream>>>(Pg, W2t, out);
  k6_lb<<<1, 1, 0, stream>>>(usage, out + (size_t)16777216);
}

// Round 4
// 272.265 us; speedup vs baseline: 2.1562x; 1.0218x over previous
//
#include <hip/hip_runtime.h>

// Problem constants: B=8, N=4096, DIM=C=512, E=8, K=2, H=16, T=B*N=32768
#define T_TOK 32768
#define C_DIM 512
#define N_SEQ 4096

typedef unsigned short ushort_t;
typedef unsigned int uint_t;
typedef __attribute__((ext_vector_type(8))) _Float16 half8;
typedef __attribute__((ext_vector_type(4))) float f32x4;

static __device__ __forceinline__ ushort_t f2h_bits(float f) {
  _Float16 h = (_Float16)f;
  return __builtin_bit_cast(ushort_t, h);
}
static __device__ __forceinline__ float h_bits2f(ushort_t u) {
  return (float)__builtin_bit_cast(_Float16, u);
}

// LDS tile: 128 rows x 32 f16 (64B rows), stored in 16B slots with XOR swizzle
// slot p holds logical (r = p>>2, q = (p&3) ^ ((r>>1)&3)). Fragment read for
// (row r, k-quarter q) -> ushort off r*32 + (q ^ ((r>>1)&3))*8. This gives
// 2-way (free) bank aliasing on ds_read_b128 instead of 8-way.
static __device__ __forceinline__ half8 frag_ld(const ushort_t* base, int r, int q) {
  const int off = r * 32 + ((q ^ ((r >> 1) & 3)) * 8);  // in ushorts
  return *(const half8*)(base + off);
}

#define GLOAD_LDS(gptr, lptr)                                                  \
  __builtin_amdgcn_global_load_lds(                                            \
      (const __attribute__((address_space(1))) uint_t*)(gptr),                 \
      (__attribute__((address_space(3))) uint_t*)(lptr), 16, 0, 0)

// ---------------------------------------------------------------------------
// prep (fused): all blocks convert x -> f16 hi/lo; blocks <1024 also convert
// wg1 -> hi/lo, w1 -> W1t, w2+b2 -> W2t; block 4096 zeroes stats+usage.
// ---------------------------------------------------------------------------
__global__ __launch_bounds__(256) void prep(
    const float* __restrict__ X, const float* __restrict__ wg1,
    const float* __restrict__ w1, const float* __restrict__ w2,
    const float* __restrict__ b2, ushort_t* __restrict__ Ahi,
    ushort_t* __restrict__ Alo, ushort_t* __restrict__ Whi,
    ushort_t* __restrict__ Wlo, ushort_t* __restrict__ W1t,
    ushort_t* __restrict__ W2t, float* __restrict__ stats,
    float* __restrict__ usage) {
  const int idx = blockIdx.x * 256 + threadIdx.x;
  // x conversion: 8 elems/thread, grid 8192 covers 16.7M
  {
    const size_t i0 = (size_t)idx * 8;
    float4 a = *(const float4*)(X + i0);
    float4 b = *(const float4*)(X + i0 + 4);
    float v[8] = {a.x, a.y, a.z, a.w, b.x, b.y, b.z, b.w};
    ushort_t hi[8], lo[8];
#pragma unroll
    for (int j = 0; j < 8; ++j) {
      hi[j] = f2h_bits(v[j]);
      lo[j] = f2h_bits(v[j] - h_bits2f(hi[j]));
    }
    *(uint4*)(Ahi + i0) = *(uint4*)hi;
    *(uint4*)(Alo + i0) = *(uint4*)lo;
  }
  if (blockIdx.x < 1024) {
    {
      const float v = wg1[idx];
      const ushort_t h = f2h_bits(v);
      Whi[idx] = h;
      Wlo[idx] = f2h_bits(v - h_bits2f(h));
    }
    if (idx < 65536) {
      const int eh = idx >> 9, c = idx & 511;
      const int e = eh >> 4, hh = eh & 15;
      W1t[idx] = f2h_bits(w1[((size_t)e * 512 + c) * 16 + hh]);
    }
    if (idx < 81920) {
      const int c = idx / 160, k = idx - c * 160;
      float v = 0.f;
      if (k < 128) {
        const int e = k >> 4, hh = k & 15;
        v = w2[((size_t)e * 16 + hh) * 512 + c];
      } else if (k < 136) {
        v = b2[(size_t)(k - 128) * 512 + c];
      }
      W2t[c * 160 + k] = f2h_bits(v);
    }
  }
  if (blockIdx.x == 4096) {
    float4 z = {0.f, 0.f, 0.f, 0.f};
    *(float4*)&stats[threadIdx.x * 4] = z;  // 256*4 = 1024 floats
    if (threadIdx.x < 8) usage[threadIdx.x] = 0.f;
  }
}

// ---------------------------------------------------------------------------
// K1: gate GEMM via split-f16 MFMA, h = (xhi+xlo)@(whi+wlo)^T + bg1
// (3 products, lo*lo dropped ~2^-24). 128x128 tile, BK=32, 4 waves,
// global_load_lds staging. Epilogue: h fp32 + BN partial sums (fp32 atomics).
// ---------------------------------------------------------------------------
__global__ __launch_bounds__(256) void k1_mfma(
    const ushort_t* __restrict__ Ahi, const ushort_t* __restrict__ Alo,
    const ushort_t* __restrict__ Whi, const ushort_t* __restrict__ Wlo,
    const float* __restrict__ bg1, float* __restrict__ H,
    float* __restrict__ stats) {
  __shared__ ushort_t sAh[4096], sAl[4096], sBh[4096], sBl[4096];
  const int tid = threadIdx.x, lane = tid & 63, w = tid >> 6;
  const int wm = w >> 1, wn = w & 1;
  const int m0 = blockIdx.y * 128, n0 = blockIdx.x * 128;

  const ushort_t* gsrc;
  ushort_t* lbase;
  int rowbase;
  if (w == 0)      { gsrc = Ahi; lbase = sAh; rowbase = m0; }
  else if (w == 1) { gsrc = Alo; lbase = sAl; rowbase = m0; }
  else if (w == 2) { gsrc = Whi; lbase = sBh; rowbase = n0; }
  else             { gsrc = Wlo; lbase = sBl; rowbase = n0; }

  f32x4 acc[4][4] = {};
  const int cl = lane & 15, qf = lane >> 4;

  for (int kc = 0; kc < 16; ++kc) {
    const int k0 = kc * 32;
    __syncthreads();
#pragma unroll
    for (int j = 0; j < 8; ++j) {
      const int p = j * 64 + lane;
      const int r = p >> 2, q = (p & 3) ^ ((r >> 1) & 3);
      GLOAD_LDS(gsrc + (size_t)(rowbase + r) * 512 + k0 + q * 8, lbase + j * 512);
    }
    __syncthreads();
    half8 ah[4], al[4], bh[4], bl[4];
#pragma unroll
    for (int f = 0; f < 4; ++f) {
      ah[f] = frag_ld(sAh, wm * 64 + f * 16 + cl, qf);
      al[f] = frag_ld(sAl, wm * 64 + f * 16 + cl, qf);
      bh[f] = frag_ld(sBh, wn * 64 + f * 16 + cl, qf);
      bl[f] = frag_ld(sBl, wn * 64 + f * 16 + cl, qf);
    }
#pragma unroll
    for (int i = 0; i < 4; ++i)
#pragma unroll
      for (int j = 0; j < 4; ++j) {
        acc[i][j] = __builtin_amdgcn_mfma_f32_16x16x32_f16(ah[i], bh[j], acc[i][j], 0, 0, 0);
        acc[i][j] = __builtin_amdgcn_mfma_f32_16x16x32_f16(ah[i], bl[j], acc[i][j], 0, 0, 0);
        acc[i][j] = __builtin_amdgcn_mfma_f32_16x16x32_f16(al[i], bh[j], acc[i][j], 0, 0, 0);
      }
  }

  // epilogue: +bg1, store h, BN partial stats
  float s[4] = {0, 0, 0, 0}, qs[4] = {0, 0, 0, 0};
  const int rq = lane >> 4;
#pragma unroll
  for (int nf = 0; nf < 4; ++nf) {
    const int col = n0 + wn * 64 + nf * 16 + cl;
    const float bv = bg1[col];
#pragma unroll
    for (int mf = 0; mf < 4; ++mf) {
      const int row = m0 + wm * 64 + mf * 16 + rq * 4;
#pragma unroll
      for (int i = 0; i < 4; ++i) {
        const float v = acc[mf][nf][i] + bv;
        H[(size_t)(row + i) * 512 + col] = v;
        s[nf] += v;
        qs[nf] += v * v;
      }
    }
  }
#pragma unroll
  for (int nf = 0; nf < 4; ++nf) {
    s[nf] += __shfl_xor(s[nf], 16, 64);
    qs[nf] += __shfl_xor(qs[nf], 16, 64);
    s[nf] += __shfl_xor(s[nf], 32, 64);
    qs[nf] += __shfl_xor(qs[nf], 32, 64);
  }
  if (lane < 16) {
#pragma unroll
    for (int nf = 0; nf < 4; ++nf) {
      const int col = n0 + wn * 64 + nf * 16 + cl;
      atomicAdd(&stats[col], s[nf]);
      atomicAdd(&stats[512 + col], qs[nf]);
    }
  }
}

// ---------------------------------------------------------------------------
// K4: gating (top-2 + softmax + usage), with BN finalize folded in: each
// block recomputes scale/shift from stats (deterministic double math).
// ---------------------------------------------------------------------------
__global__ __launch_bounds__(256) void k4_gate(
    const float* __restrict__ H, const float* __restrict__ stats,
    const float* __restrict__ gamma, const float* __restrict__ beta,
    const float* __restrict__ wg2, const float* __restrict__ bg2,
    int* __restrict__ selE, float* __restrict__ selW,
    float* __restrict__ usage) {
  __shared__ float scsh_l[1024];
  __shared__ float lus[8];
  if (threadIdx.x < 8) lus[threadIdx.x] = 0.f;
#pragma unroll
  for (int rep = 0; rep < 2; ++rep) {
    const int c = threadIdx.x + rep * 256;
    const double mu = (double)stats[c] * (1.0 / (double)T_TOK);
    const double var = (double)stats[512 + c] * (1.0 / (double)T_TOK) - mu * mu;
    const double rstd = 1.0 / sqrt(var + 1e-5);
    const float scv = (float)((double)gamma[c] * rstd);
    scsh_l[c] = scv;
    scsh_l[512 + c] = beta[c] - (float)mu * scv;
  }
  __syncthreads();

  const int wv = threadIdx.x >> 6, lane = threadIdx.x & 63;
  const int cb = lane * 8;

  float sc[8], sh[8];
#pragma unroll
  for (int i = 0; i < 8; ++i) {
    sc[i] = scsh_l[cb + i];
    sh[i] = scsh_l[512 + cb + i];
  }
  float wg[8][8];
#pragma unroll
  for (int e = 0; e < 8; ++e)
#pragma unroll
    for (int i = 0; i < 8; ++i) wg[e][i] = wg2[e * C_DIM + cb + i];
  float bg[8];
#pragma unroll
  for (int e = 0; e < 8; ++e) bg[e] = bg2[e];

  for (int it = 0; it < 16; ++it) {
    const int t = blockIdx.x * 64 + wv * 16 + it;
    const float* hr = H + (size_t)t * C_DIM + cb;
    float4 h0 = *(const float4*)hr;
    float4 h1 = *(const float4*)(hr + 4);
    float y[8] = {h0.x, h0.y, h0.z, h0.w, h1.x, h1.y, h1.z, h1.w};
#pragma unroll
    for (int i = 0; i < 8; ++i) y[i] = fmaxf(fmaf(y[i], sc[i], sh[i]), 0.f);

    float lg[8];
#pragma unroll
    for (int e = 0; e < 8; ++e) {
      float sum = 0.f;
#pragma unroll
      for (int i = 0; i < 8; ++i) sum = fmaf(y[i], wg[e][i], sum);
      lg[e] = sum;
    }
#pragma unroll
    for (int d = 1; d < 64; d <<= 1)
#pragma unroll
      for (int e = 0; e < 8; ++e) lg[e] += __shfl_xor(lg[e], d, 64);
#pragma unroll
    for (int e = 0; e < 8; ++e) lg[e] += bg[e];

    float v1 = lg[0]; int i1 = 0;
#pragma unroll
    for (int e = 1; e < 8; ++e)
      if (lg[e] > v1) { v1 = lg[e]; i1 = e; }
    float v2 = -3.4e38f; int i2 = 0;
#pragma unroll
    for (int e = 0; e < 8; ++e)
      if (e != i1 && lg[e] > v2) { v2 = lg[e]; i2 = e; }

    const float p = expf(v2 - v1);
    const float rw = 1.f / (1.f + p);
    const float w0 = rw, w1 = p * rw;

    if (lane == 0) {
      selE[2 * t] = i1;
      selE[2 * t + 1] = i2;
      selW[2 * t] = w0;
      selW[2 * t + 1] = w1;
      atomicAdd(&lus[i1], w0);
      atomicAdd(&lus[i2], w1);
    }
  }
  __syncthreads();
  if (threadIdx.x < 8) atomicAdd(&usage[threadIdx.x], lus[threadIdx.x]);
}

// ---------------------------------------------------------------------------
// K5a: FC1 dense-ified MFMA: C[128 tok x 128 eh] = x_hi @ W1t^T, then
// +b1, relu, * gate weight (0 if unselected) -> P f16 [T][160] global.
// Ext cols 128+e hold gate weight (for the b2 K-extension), 136..159 zero.
// ---------------------------------------------------------------------------
__global__ __launch_bounds__(256) void k5a_fc1(
    const ushort_t* __restrict__ Ahi, const ushort_t* __restrict__ W1t,
    const float* __restrict__ b1, const int* __restrict__ selE,
    const float* __restrict__ selW, ushort_t* __restrict__ Pg) {
  __shared__ ushort_t sA[4096], sB[4096];
  __shared__ ushort_t Pl[128 * 160];
  __shared__ float wtab[128 * 8];
  const int tid = threadIdx.x, lane = tid & 63, w = tid >> 6;
  const int wm = w >> 1, wn = w & 1;
  const int t0 = blockIdx.x * 128;

#pragma unroll
  for (int i = 0; i < 4; ++i) wtab[tid * 4 + i] = 0.f;
  {
    uint4 z = {0, 0, 0, 0};
    const int row = tid >> 1, hf = tid & 1;
    *(uint4*)&Pl[row * 160 + 128 + hf * 16] = z;
    *(uint4*)&Pl[row * 160 + 136 + hf * 16] = z;
  }
  __syncthreads();
  {
    const int t = tid >> 1, s = tid & 1;
    const int e = selE[(size_t)(t0 + t) * 2 + s];
    const float wv = selW[(size_t)(t0 + t) * 2 + s];
    wtab[t * 8 + e] = wv;
    Pl[t * 160 + 128 + e] = f2h_bits(wv);
  }

  f32x4 acc[4][4] = {};
  const int cl = lane & 15, qf = lane >> 4;
  for (int kc = 0; kc < 16; ++kc) {
    const int k0 = kc * 32;
    __syncthreads();
    const ushort_t* gs = (w < 2) ? Ahi : W1t;
    ushort_t* lb = (w < 2) ? sA : sB;
    const int rbase = (w < 2) ? t0 : 0;
    const int wh = w & 1;
#pragma unroll
    for (int j = 0; j < 4; ++j) {
      const int p = wh * 256 + j * 64 + lane;
      const int r = p >> 2, q = (p & 3) ^ ((r >> 1) & 3);
      GLOAD_LDS(gs + (size_t)(rbase + r) * 512 + k0 + q * 8, lb + wh * 2048 + j * 512);
    }
    __syncthreads();
    half8 af[4], bf[4];
#pragma unroll
    for (int f = 0; f < 4; ++f) {
      af[f] = frag_ld(sA, wm * 64 + f * 16 + cl, qf);
      bf[f] = frag_ld(sB, wn * 64 + f * 16 + cl, qf);
    }
#pragma unroll
    for (int i = 0; i < 4; ++i)
#pragma unroll
      for (int j = 0; j < 4; ++j)
        acc[i][j] = __builtin_amdgcn_mfma_f32_16x16x32_f16(af[i], bf[j], acc[i][j], 0, 0, 0);
  }

  {
    const int rq = lane >> 4;
#pragma unroll
    for (int nf = 0; nf < 4; ++nf) {
      const int col = wn * 64 + nf * 16 + cl;
      const float bv = b1[col];
      const int e = wn * 4 + nf;  // col>>4
#pragma unroll
      for (int mf = 0; mf < 4; ++mf) {
        const int row = wm * 64 + mf * 16 + rq * 4;
#pragma unroll
        for (int i = 0; i < 4; ++i) {
          const float v = fmaxf(acc[mf][nf][i] + bv, 0.f) * wtab[(row + i) * 8 + e];
          Pl[(row + i) * 160 + col] = f2h_bits(v);
        }
      }
    }
  }
  __syncthreads();
  {
    const int row = tid >> 1, half = tid & 1;
    const uint4* src = (const uint4*)&Pl[row * 160 + half * 80];
    uint4* dst = (uint4*)(Pg + (size_t)(t0 + row) * 160 + half * 80);
#pragma unroll
    for (int j = 0; j < 10; ++j) dst[j] = src[j];
  }
}

// ---------------------------------------------------------------------------
// K5b: FC2: Out[128 tok x 512 c] = P_ext @ W2t_ext^T (K=160 incl b2 cols),
// 4 n-chunks of 128, LDS transpose -> coalesced [B,C,N]. Block 0 also
// computes lb_loss (usage is final after k4).
// ---------------------------------------------------------------------------
__global__ __launch_bounds__(256) void k5b_fc2(
    const ushort_t* __restrict__ Pg, const ushort_t* __restrict__ W2t,
    const float* __restrict__ usage, float* __restrict__ Out) {
  __shared__ ushort_t sA[4096], sB[4096];
  __shared__ float ys[128 * 68];
  const int tid = threadIdx.x, lane = tid & 63, w = tid >> 6;
  const int wm = w >> 1, wn = w & 1;
  const int t0 = blockIdx.x * 128;
  const int bi = t0 >> 12, n0 = t0 & 4095;
  const int cl = lane & 15, qf = lane >> 4, rq = lane >> 4;

  if (blockIdx.x == 0 && tid == 0) {
    float s = 0.f;
#pragma unroll
    for (int e = 0; e < 8; ++e) {
      const float u = usage[e] * (1.f / (float)T_TOK);
      s += u * u;
    }
    Out[(size_t)16777216] = s * 8.f;
  }

  for (int nc = 0; nc < 4; ++nc) {
    f32x4 acc[4][4] = {};
    for (int kc = 0; kc < 5; ++kc) {
      const int k0 = kc * 32;
      __syncthreads();
      const ushort_t* gs = (w < 2) ? Pg : W2t;
      ushort_t* lb = (w < 2) ? sA : sB;
      const int rbase = (w < 2) ? t0 : nc * 128;
      const int wh = w & 1;
#pragma unroll
      for (int j = 0; j < 4; ++j) {
        const int p = wh * 256 + j * 64 + lane;
        const int r = p >> 2, q = (p & 3) ^ ((r >> 1) & 3);
        GLOAD_LDS(gs + (size_t)(rbase + r) * 160 + k0 + q * 8, lb + wh * 2048 + j * 512);
      }
      __syncthreads();
      half8 af[4], bf4[4];
#pragma unroll
      for (int f = 0; f < 4; ++f) {
        af[f] = frag_ld(sA, wm * 64 + f * 16 + cl, qf);
        bf4[f] = frag_ld(sB, wn * 64 + f * 16 + cl, qf);
      }
#pragma unroll
      for (int i = 0; i < 4; ++i)
#pragma unroll
        for (int j = 0; j < 4; ++j)
          acc[i][j] = __builtin_amdgcn_mfma_f32_16x16x32_f16(af[i], bf4[j], acc[i][j], 0, 0, 0);
    }
#pragma unroll
    for (int half = 0; half < 2; ++half) {
      __syncthreads();
      if (wm == half) {
#pragma unroll
        for (int nf = 0; nf < 4; ++nf) {
          const int c = wn * 64 + nf * 16 + cl;
#pragma unroll
          for (int mf = 0; mf < 4; ++mf) {
            const int trow = mf * 16 + rq * 4;
#pragma unroll
            for (int i = 0; i < 4; ++i) ys[c * 68 + trow + i] = acc[mf][nf][i];
          }
        }
      }
      __syncthreads();
#pragma unroll
      for (int pass = 0; pass < 8; ++pass) {
        const int c = pass * 16 + (tid >> 4);
        const int f4 = tid & 15;
        float4 v = *(const float4*)&ys[c * 68 + f4 * 4];
        *(float4*)&Out[((size_t)(bi * 512 + nc * 128 + c)) * 4096 + n0 + half * 64 + f4 * 4] = v;
      }
    }
  }
}

// ---------------------------------------------------------------------------
extern "C" void kernel_launch(void* const* d_in, const int* in_sizes, int n_in,
                              void* d_out, int out_size, void* d_ws, size_t ws_size,
                              hipStream_t stream) {
  const float* x     = (const float*)d_in[0];
  const float* wg1   = (const float*)d_in[1];
  const float* bg1   = (const float*)d_in[2];
  const float* gamma = (const float*)d_in[3];
  const float* beta  = (const float*)d_in[4];
  const float* wg2   = (const float*)d_in[5];
  const float* bg2   = (const float*)d_in[6];
  const float* w1    = (const float*)d_in[7];
  const float* b1    = (const float*)d_in[8];
  const float* w2    = (const float*)d_in[9];
  const float* b2    = (const float*)d_in[10];
  float* out = (float*)d_out;

  // Workspace layout (bytes):
  char* ws = (char*)d_ws;
  float*    h     = (float*)ws;                          // 67108864
  ushort_t* Ahi   = (ushort_t*)(ws + 67108864);          // 33554432
  ushort_t* Alo   = (ushort_t*)(ws + 100663296);         // 33554432
  ushort_t* Pg    = (ushort_t*)(ws + 134217728);         // 10485760
  ushort_t* Whi   = (ushort_t*)(ws + 144703488);         // 524288
  ushort_t* Wlo   = (ushort_t*)(ws + 145227776);         // 524288
  ushort_t* W1t   = (ushort_t*)(ws + 145752064);         // 131072
  ushort_t* W2t   = (ushort_t*)(ws + 145883136);         // 163840
  float*    stats = (float*)(ws + 146046976);            // 4096
  float*    usage = (float*)(ws + 146051072);            // 32 (+pad)
  int*      selE  = (int*)(ws + 146051104);              // 262144
  float*    selW  = (float*)(ws + 146313248);            // 262144

  prep<<<8192, 256, 0, stream>>>(x, wg1, w1, w2, b2, Ahi, Alo, Whi, Wlo, W1t,
                                 W2t, stats, usage);
  k1_mfma<<<dim3(4, 256), 256, 0, stream>>>(Ahi, Alo, Whi, Wlo, bg1, h, stats);
  k4_gate<<<512, 256, 0, stream>>>(h, stats, gamma, beta, wg2, bg2, selE, selW,
                                   usage);
  k5a_fc1<<<256, 256, 0, stream>>>(Ahi, W1t, b1, selE, selW, Pg);
  k5b_fc2<<<256, 256, 0, stream>>>(Pg, W2t, usage, out);
}

// Round 6
// 270.197 us; speedup vs baseline: 2.1727x; 1.0077x over previous
//
#include <hip/hip_runtime.h>

// Problem constants: B=8, N=4096, DIM=C=512, E=8, K=2, H=16, T=B*N=32768
#define T_TOK 32768
#define C_DIM 512
#define N_SEQ 4096

typedef unsigned short ushort_t;
typedef unsigned int uint_t;
typedef __attribute__((ext_vector_type(8))) _Float16 half8;
typedef __attribute__((ext_vector_type(4))) float f32x4;

static __device__ __forceinline__ ushort_t f2h_bits(float f) {
  _Float16 h = (_Float16)f;
  return __builtin_bit_cast(ushort_t, h);
}
static __device__ __forceinline__ float h_bits2f(ushort_t u) {
  return (float)__builtin_bit_cast(_Float16, u);
}

// LDS tile: 128 rows x 32 f16 (64B rows), stored in 16B slots with XOR swizzle
// slot p holds logical (r = p>>2, q = (p&3) ^ ((r>>1)&3)). Fragment read for
// (row r, k-quarter q) -> ushort off r*32 + (q ^ ((r>>1)&3))*8 => 2-way (free)
// bank aliasing on ds_read_b128 instead of 8-way.
static __device__ __forceinline__ half8 frag_ld(const ushort_t* base, int r, int q) {
  const int off = r * 32 + ((q ^ ((r >> 1) & 3)) * 8);  // in ushorts
  return *(const half8*)(base + off);
}

#define GLOAD_LDS(gptr, lptr)                                                  \
  __builtin_amdgcn_global_load_lds(                                            \
      (const __attribute__((address_space(1))) uint_t*)(gptr),                 \
      (__attribute__((address_space(3))) uint_t*)(lptr), 16, 0, 0)

// ---------------------------------------------------------------------------
// prep (fused): all blocks convert x -> f16 hi/lo; blocks <1024 also convert
// wg1 -> hi/lo, w1 -> W1t, w2+b2 -> W2t; block 4096 zeroes stats+usage+done.
// ---------------------------------------------------------------------------
__global__ __launch_bounds__(256) void prep(
    const float* __restrict__ X, const float* __restrict__ wg1,
    const float* __restrict__ w1, const float* __restrict__ w2,
    const float* __restrict__ b2, ushort_t* __restrict__ Ahi,
    ushort_t* __restrict__ Alo, ushort_t* __restrict__ Whi,
    ushort_t* __restrict__ Wlo, ushort_t* __restrict__ W1t,
    ushort_t* __restrict__ W2t, float* __restrict__ stats,
    float* __restrict__ usage, uint_t* __restrict__ done) {
  const int idx = blockIdx.x * 256 + threadIdx.x;
  {
    const size_t i0 = (size_t)idx * 8;
    float4 a = *(const float4*)(X + i0);
    float4 b = *(const float4*)(X + i0 + 4);
    float v[8] = {a.x, a.y, a.z, a.w, b.x, b.y, b.z, b.w};
    ushort_t hi[8], lo[8];
#pragma unroll
    for (int j = 0; j < 8; ++j) {
      hi[j] = f2h_bits(v[j]);
      lo[j] = f2h_bits(v[j] - h_bits2f(hi[j]));
    }
    *(uint4*)(Ahi + i0) = *(uint4*)hi;
    *(uint4*)(Alo + i0) = *(uint4*)lo;
  }
  if (blockIdx.x < 1024) {
    {
      const float v = wg1[idx];
      const ushort_t h = f2h_bits(v);
      Whi[idx] = h;
      Wlo[idx] = f2h_bits(v - h_bits2f(h));
    }
    if (idx < 65536) {
      const int eh = idx >> 9, c = idx & 511;
      const int e = eh >> 4, hh = eh & 15;
      W1t[idx] = f2h_bits(w1[((size_t)e * 512 + c) * 16 + hh]);
    }
    if (idx < 81920) {
      const int c = idx / 160, k = idx - c * 160;
      float v = 0.f;
      if (k < 128) {
        const int e = k >> 4, hh = k & 15;
        v = w2[((size_t)e * 16 + hh) * 512 + c];
      } else if (k < 136) {
        v = b2[(size_t)(k - 128) * 512 + c];
      }
      W2t[c * 160 + k] = f2h_bits(v);
    }
  }
  if (blockIdx.x == 4096) {
    float4 z = {0.f, 0.f, 0.f, 0.f};
    *(float4*)&stats[threadIdx.x * 4] = z;
    if (threadIdx.x < 8) usage[threadIdx.x] = 0.f;
    if (threadIdx.x == 8) *done = 0u;
  }
}

// ---------------------------------------------------------------------------
// K1: gate GEMM via split-f16 MFMA, h = (xhi+xlo)@(whi+wlo)^T + bg1.
// 1-D grid 1024; decode puts the 4 n-siblings of an m-strip 8 apart in
// linear ID -> same XCD (b%8) and near-simultaneous dispatch, so the A
// row-strip is fetched from HBM once per XCD-group instead of 4x.
// ---------------------------------------------------------------------------
__global__ __launch_bounds__(256) void k1_mfma(
    const ushort_t* __restrict__ Ahi, const ushort_t* __restrict__ Alo,
    const ushort_t* __restrict__ Whi, const ushort_t* __restrict__ Wlo,
    const float* __restrict__ bg1, float* __restrict__ H,
    float* __restrict__ stats) {
  __shared__ ushort_t sAh[4096], sAl[4096], sBh[4096], sBl[4096];
  const int tid = threadIdx.x, lane = tid & 63, w = tid >> 6;
  const int wm = w >> 1, wn = w & 1;
  const int b = blockIdx.x;
  const int m0 = ((b & 7) | ((b >> 5) << 3)) * 128;  // b = 32*(m>>3)+8*n+(m&7)
  const int n0 = ((b >> 3) & 3) * 128;

  const ushort_t* gsrc;
  ushort_t* lbase;
  int rowbase;
  if (w == 0)      { gsrc = Ahi; lbase = sAh; rowbase = m0; }
  else if (w == 1) { gsrc = Alo; lbase = sAl; rowbase = m0; }
  else if (w == 2) { gsrc = Whi; lbase = sBh; rowbase = n0; }
  else             { gsrc = Wlo; lbase = sBl; rowbase = n0; }

  f32x4 acc[4][4] = {};
  const int cl = lane & 15, qf = lane >> 4;

  for (int kc = 0; kc < 16; ++kc) {
    const int k0 = kc * 32;
    __syncthreads();
#pragma unroll
    for (int j = 0; j < 8; ++j) {
      const int p = j * 64 + lane;
      const int r = p >> 2, q = (p & 3) ^ ((r >> 1) & 3);
      GLOAD_LDS(gsrc + (size_t)(rowbase + r) * 512 + k0 + q * 8, lbase + j * 512);
    }
    __syncthreads();
    half8 ah[4], al[4], bh[4], bl[4];
#pragma unroll
    for (int f = 0; f < 4; ++f) {
      ah[f] = frag_ld(sAh, wm * 64 + f * 16 + cl, qf);
      al[f] = frag_ld(sAl, wm * 64 + f * 16 + cl, qf);
      bh[f] = frag_ld(sBh, wn * 64 + f * 16 + cl, qf);
      bl[f] = frag_ld(sBl, wn * 64 + f * 16 + cl, qf);
    }
#pragma unroll
    for (int i = 0; i < 4; ++i)
#pragma unroll
      for (int j = 0; j < 4; ++j) {
        acc[i][j] = __builtin_amdgcn_mfma_f32_16x16x32_f16(ah[i], bh[j], acc[i][j], 0, 0, 0);
        acc[i][j] = __builtin_amdgcn_mfma_f32_16x16x32_f16(ah[i], bl[j], acc[i][j], 0, 0, 0);
        acc[i][j] = __builtin_amdgcn_mfma_f32_16x16x32_f16(al[i], bh[j], acc[i][j], 0, 0, 0);
      }
  }

  float s[4] = {0, 0, 0, 0}, qs[4] = {0, 0, 0, 0};
  const int rq = lane >> 4;
#pragma unroll
  for (int nf = 0; nf < 4; ++nf) {
    const int col = n0 + wn * 64 + nf * 16 + cl;
    const float bv = bg1[col];
#pragma unroll
    for (int mf = 0; mf < 4; ++mf) {
      const int row = m0 + wm * 64 + mf * 16 + rq * 4;
#pragma unroll
      for (int i = 0; i < 4; ++i) {
        const float v = acc[mf][nf][i] + bv;
        H[(size_t)(row + i) * 512 + col] = v;
        s[nf] += v;
        qs[nf] += v * v;
      }
    }
  }
#pragma unroll
  for (int nf = 0; nf < 4; ++nf) {
    s[nf] += __shfl_xor(s[nf], 16, 64);
    qs[nf] += __shfl_xor(qs[nf], 16, 64);
    s[nf] += __shfl_xor(s[nf], 32, 64);
    qs[nf] += __shfl_xor(qs[nf], 32, 64);
  }
  if (lane < 16) {
#pragma unroll
    for (int nf = 0; nf < 4; ++nf) {
      const int col = n0 + wn * 64 + nf * 16 + cl;
      atomicAdd(&stats[col], s[nf]);
      atomicAdd(&stats[512 + col], qs[nf]);
    }
  }
}

// ---------------------------------------------------------------------------
// K5 (fused gate+FC1+FC2): per block of 128 tokens:
//   (a) BN finalize (recomputed) + gating top-2/softmax -> wtab + P ext cols
//   (b) FC1 MFMA (Ahi @ W1t^T), epilogue relu*gate -> Pl f16 [128][168] LDS
//   (c) FC2 MFMA (Pl @ W2t^T, K=160 incl b2 cols), LDS transpose -> [B,C,N]
//   lb_loss by last-finisher ticket on `done`.
// Pl width 168: A-frag stride 336B -> 2-way (free) LDS bank aliasing.
// NOTE uint4 = 8 f16 elements: ext-col zeroing [128,160) needs the two-store
// 128+hf*16 / 136+hf*16 pattern (this exact span bug caused NaN twice).
// ---------------------------------------------------------------------------
__global__ __launch_bounds__(256) void k5_fused(
    const ushort_t* __restrict__ Ahi, const ushort_t* __restrict__ W1t,
    const ushort_t* __restrict__ W2t, const float* __restrict__ b1,
    const float* __restrict__ H, const float* __restrict__ stats,
    const float* __restrict__ gamma, const float* __restrict__ beta,
    const float* __restrict__ wg2, const float* __restrict__ bg2,
    float* __restrict__ usage, uint_t* __restrict__ done,
    float* __restrict__ Out) {
  __shared__ ushort_t sA[4096], sB[4096];
  __shared__ ushort_t Pl[128 * 168];
  __shared__ float wtab[128 * 8];
  __shared__ float ys[128 * 68];
  __shared__ float scsh_l[1024];
  __shared__ float lus[8];

  const int tid = threadIdx.x, lane = tid & 63, w = tid >> 6;
  const int wm = w >> 1, wn = w & 1;
  const int t0 = blockIdx.x * 128;
  const int bi = t0 >> 12, n0 = t0 & 4095;
  const int cl = lane & 15, qf = lane >> 4, rq = lane >> 4;

  // ---- init: zero wtab, P ext cols [128,160); BN scale/shift --------------
  if (tid < 8) lus[tid] = 0.f;
#pragma unroll
  for (int i = 0; i < 4; ++i) wtab[tid * 4 + i] = 0.f;
  {
    uint4 z = {0, 0, 0, 0};
    const int row = tid >> 1, hf = tid & 1;
    *(uint4*)&Pl[row * 168 + 128 + hf * 16] = z;  // hf=0: 128..135, hf=1: 144..151
    *(uint4*)&Pl[row * 168 + 136 + hf * 16] = z;  // hf=0: 136..143, hf=1: 152..159
  }
#pragma unroll
  for (int rep = 0; rep < 2; ++rep) {
    const int c = tid + rep * 256;
    const double mu = (double)stats[c] * (1.0 / (double)T_TOK);
    const double var = (double)stats[512 + c] * (1.0 / (double)T_TOK) - mu * mu;
    const double rstd = 1.0 / sqrt(var + 1e-5);
    const float scv = (float)((double)gamma[c] * rstd);
    scsh_l[c] = scv;
    scsh_l[512 + c] = beta[c] - (float)mu * scv;
  }
  __syncthreads();

  // ---- (a) gating: 4 waves x 32 tokens ------------------------------------
  {
    const int cb = lane * 8;
    float sc[8], sh[8];
#pragma unroll
    for (int i = 0; i < 8; ++i) {
      sc[i] = scsh_l[cb + i];
      sh[i] = scsh_l[512 + cb + i];
    }
    float wg[8][8];
#pragma unroll
    for (int e = 0; e < 8; ++e)
#pragma unroll
      for (int i = 0; i < 8; ++i) wg[e][i] = wg2[e * C_DIM + cb + i];
    float bg[8];
#pragma unroll
    for (int e = 0; e < 8; ++e) bg[e] = bg2[e];

#pragma unroll 2
    for (int it = 0; it < 32; ++it) {
      const int tl = w * 32 + it;
      const float* hr = H + (size_t)(t0 + tl) * C_DIM + cb;
      float4 h0 = *(const float4*)hr;
      float4 h1 = *(const float4*)(hr + 4);
      float y[8] = {h0.x, h0.y, h0.z, h0.w, h1.x, h1.y, h1.z, h1.w};
#pragma unroll
      for (int i = 0; i < 8; ++i) y[i] = fmaxf(fmaf(y[i], sc[i], sh[i]), 0.f);

      float lg[8];
#pragma unroll
      for (int e = 0; e < 8; ++e) {
        float sum = 0.f;
#pragma unroll
        for (int i = 0; i < 8; ++i) sum = fmaf(y[i], wg[e][i], sum);
        lg[e] = sum;
      }
#pragma unroll
      for (int d = 1; d < 64; d <<= 1)
#pragma unroll
        for (int e = 0; e < 8; ++e) lg[e] += __shfl_xor(lg[e], d, 64);
#pragma unroll
      for (int e = 0; e < 8; ++e) lg[e] += bg[e];

      float v1 = lg[0]; int i1 = 0;
#pragma unroll
      for (int e = 1; e < 8; ++e)
        if (lg[e] > v1) { v1 = lg[e]; i1 = e; }
      float v2 = -3.4e38f; int i2 = 0;
#pragma unroll
      for (int e = 0; e < 8; ++e)
        if (e != i1 && lg[e] > v2) { v2 = lg[e]; i2 = e; }

      const float p = expf(v2 - v1);
      const float rw = 1.f / (1.f + p);
      const float w0 = rw, w1 = p * rw;

      if (lane == 0) {
        wtab[tl * 8 + i1] = w0;
        wtab[tl * 8 + i2] = w1;
        Pl[tl * 168 + 128 + i1] = f2h_bits(w0);
        Pl[tl * 168 + 128 + i2] = f2h_bits(w1);
        atomicAdd(&lus[i1], w0);
        atomicAdd(&lus[i2], w1);
      }
    }
  }
  __syncthreads();
  if (tid < 8) atomicAdd(&usage[tid], lus[tid]);
  __syncthreads();
  if (tid == 0) {
    __threadfence();
    const uint_t ticket = atomicAdd(done, 1u);
    if (ticket == 255u) {
      float s = 0.f;
#pragma unroll
      for (int e = 0; e < 8; ++e) {
        const float u = atomicAdd(&usage[e], 0.f) * (1.f / (float)T_TOK);
        s += u * u;
      }
      Out[(size_t)16777216] = s * 8.f;
    }
  }

  // ---- (b) FC1: [128 tok x 128 eh] = Ahi @ W1t^T --------------------------
  f32x4 acc[4][4] = {};
  for (int kc = 0; kc < 16; ++kc) {
    const int k0 = kc * 32;
    __syncthreads();
    const ushort_t* gs = (w < 2) ? Ahi : W1t;
    ushort_t* lb = (w < 2) ? sA : sB;
    const int rbase = (w < 2) ? t0 : 0;
    const int wh = w & 1;
#pragma unroll
    for (int j = 0; j < 4; ++j) {
      const int p = wh * 256 + j * 64 + lane;
      const int r = p >> 2, q = (p & 3) ^ ((r >> 1) & 3);
      GLOAD_LDS(gs + (size_t)(rbase + r) * 512 + k0 + q * 8, lb + wh * 2048 + j * 512);
    }
    __syncthreads();
    half8 af[4], bf[4];
#pragma unroll
    for (int f = 0; f < 4; ++f) {
      af[f] = frag_ld(sA, wm * 64 + f * 16 + cl, qf);
      bf[f] = frag_ld(sB, wn * 64 + f * 16 + cl, qf);
    }
#pragma unroll
    for (int i = 0; i < 4; ++i)
#pragma unroll
      for (int j = 0; j < 4; ++j)
        acc[i][j] = __builtin_amdgcn_mfma_f32_16x16x32_f16(af[i], bf[j], acc[i][j], 0, 0, 0);
  }

  // FC1 epilogue: bias, relu, gate-weight -> Pl (e is wave-uniform per nf)
  {
#pragma unroll
    for (int nf = 0; nf < 4; ++nf) {
      const int col = wn * 64 + nf * 16 + cl;
      const float bv = b1[col];
      const int e = wn * 4 + nf;  // col>>4
#pragma unroll
      for (int mf = 0; mf < 4; ++mf) {
        const int row = wm * 64 + mf * 16 + rq * 4;
#pragma unroll
        for (int i = 0; i < 4; ++i) {
          const float v = fmaxf(acc[mf][nf][i] + bv, 0.f) * wtab[(row + i) * 8 + e];
          Pl[(row + i) * 168 + col] = f2h_bits(v);
        }
      }
    }
  }

  // ---- (c) FC2: Out[128 tok x 512 c] = Pl @ W2t^T (K=160) -----------------
  for (int nc = 0; nc < 4; ++nc) {
    f32x4 a2[4][4] = {};
    for (int kc = 0; kc < 5; ++kc) {
      const int k0 = kc * 32;
      __syncthreads();
      // stage W2t rows nc*128..+128, cols k0..k0+32 (all 4 waves)
#pragma unroll
      for (int j = 0; j < 2; ++j) {
        const int p = w * 128 + j * 64 + lane;
        const int r = p >> 2, q = (p & 3) ^ ((r >> 1) & 3);
        GLOAD_LDS(W2t + (size_t)(nc * 128 + r) * 160 + k0 + q * 8, sB + w * 1024 + j * 512);
      }
      __syncthreads();
      half8 af[4], bf4[4];
#pragma unroll
      for (int f = 0; f < 4; ++f) {
        af[f] = *(const half8*)(Pl + (wm * 64 + f * 16 + cl) * 168 + k0 + qf * 8);
        bf4[f] = frag_ld(sB, wn * 64 + f * 16 + cl, qf);
      }
#pragma unroll
      for (int i = 0; i < 4; ++i)
#pragma unroll
        for (int j = 0; j < 4; ++j)
          a2[i][j] = __builtin_amdgcn_mfma_f32_16x16x32_f16(af[i], bf4[j], a2[i][j], 0, 0, 0);
    }
    // transpose + store, two token-half phases
#pragma unroll
    for (int half = 0; half < 2; ++half) {
      __syncthreads();
      if (wm == half) {
#pragma unroll
        for (int nf = 0; nf < 4; ++nf) {
          const int c = wn * 64 + nf * 16 + cl;
#pragma unroll
          for (int mf = 0; mf < 4; ++mf) {
            const int trow = mf * 16 + rq * 4;
#pragma unroll
            for (int i = 0; i < 4; ++i) ys[c * 68 + trow + i] = a2[mf][nf][i];
          }
        }
      }
      __syncthreads();
#pragma unroll
      for (int pass = 0; pass < 8; ++pass) {
        const int c = pass * 16 + (tid >> 4);
        const int f4 = tid & 15;
        float4 v = *(const float4*)&ys[c * 68 + f4 * 4];
        *(float4*)&Out[((size_t)(bi * 512 + nc * 128 + c)) * 4096 + n0 + half * 64 + f4 * 4] = v;
      }
    }
  }
}

// ---------------------------------------------------------------------------
extern "C" void kernel_launch(void* const* d_in, const int* in_sizes, int n_in,
                              void* d_out, int out_size, void* d_ws, size_t ws_size,
                              hipStream_t stream) {
  const float* x     = (const float*)d_in[0];
  const float* wg1   = (const float*)d_in[1];
  const float* bg1   = (const float*)d_in[2];
  const float* gamma = (const float*)d_in[3];
  const float* beta  = (const float*)d_in[4];
  const float* wg2   = (const float*)d_in[5];
  const float* bg2   = (const float*)d_in[6];
  const float* w1    = (const float*)d_in[7];
  const float* b1    = (const float*)d_in[8];
  const float* w2    = (const float*)d_in[9];
  const float* b2    = (const float*)d_in[10];
  float* out = (float*)d_out;

  // Workspace layout (bytes):
  char* ws = (char*)d_ws;
  float*    h     = (float*)ws;                          // 67108864
  ushort_t* Ahi   = (ushort_t*)(ws + 67108864);          // 33554432
  ushort_t* Alo   = (ushort_t*)(ws + 100663296);         // 33554432
  ushort_t* Whi   = (ushort_t*)(ws + 134217728);         // 524288
  ushort_t* Wlo   = (ushort_t*)(ws + 134742016);         // 524288
  ushort_t* W1t   = (ushort_t*)(ws + 135266304);         // 131072
  ushort_t* W2t   = (ushort_t*)(ws + 135397376);         // 163840
  float*    stats = (float*)(ws + 135561216);            // 4096
  float*    usage = (float*)(ws + 135565312);            // 32
  uint_t*   done  = (uint_t*)(ws + 135565344);           // 4

  prep<<<8192, 256, 0, stream>>>(x, wg1, w1, w2, b2, Ahi, Alo, Whi, Wlo, W1t,
                                 W2t, stats, usage, done);
  k1_mfma<<<1024, 256, 0, stream>>>(Ahi, Alo, Whi, Wlo, bg1, h, stats);
  k5_fused<<<256, 256, 0, stream>>>(Ahi, W1t, W2t, b1, h, stats, gamma, beta,
                                    wg2, bg2, usage, done, out);
}